// Round 4
// baseline (297.241 us; speedup 1.0000x reference)
//
#include <hip/hip_runtime.h>
#include <hip/hip_bf16.h>

// Problem constants
#define B 8
#define H 3584
#define NH 28
#define KVH 4
#define HD 128
#define GS 7
#define MB 16
#define BS 256
#define R 32           // B*KVH
#define NCHUNK 64      // 64-token chunks per row (MB*BS/64)
#define SCALE 0.08838834764831845f

__device__ __forceinline__ float dot4(float4 a, float4 b) {
    return fmaf(a.x, b.x, fmaf(a.y, b.y, fmaf(a.z, b.z, a.w * b.w)));
}

template <int CTRL>
__device__ __forceinline__ float dpp_mov(float v) {
    return __int_as_float(__builtin_amdgcn_update_dpp(0, __float_as_int(v), CTRL, 0xf, 0xf, false));
}

// 16-lane-row sum via DPP (VALU pipe); every lane ends with the row sum.
__device__ __forceinline__ float red16(float v) {
    v += dpp_mov<0xB1>(v);   // quad_perm [1,0,3,2]  (xor1)
    v += dpp_mov<0x4E>(v);   // quad_perm [2,3,0,1]  (xor2)
    v += dpp_mov<0x141>(v);  // row_half_mirror
    v += dpp_mov<0x140>(v);  // row_mirror
    return v;
}

// Full 64-lane reductions: 4 DPP (VALU) + 1 ds_swizzle (xor16) + 1 shfl (xor32).
__device__ __forceinline__ float red64_sum(float v) {
    v = red16(v);
    v += __int_as_float(__builtin_amdgcn_ds_swizzle(__float_as_int(v), 0x401F)); // xor16
    v += __shfl_xor(v, 32);
    return v;
}
__device__ __forceinline__ float red64_max(float v) {
    v = fmaxf(v, dpp_mov<0xB1>(v));
    v = fmaxf(v, dpp_mov<0x4E>(v));
    v = fmaxf(v, dpp_mov<0x141>(v));
    v = fmaxf(v, dpp_mov<0x140>(v));
    v = fmaxf(v, __int_as_float(__builtin_amdgcn_ds_swizzle(__float_as_int(v), 0x401F)));
    v = fmaxf(v, __shfl_xor(v, 32));
    return v;
}

// ---------------- Kernel 1: fused QKV GEMV ----------------
// grid = 1152 blocks x 256 (4 waves). Each WAVE owns one output feature across
// all 8 batch rows; lane = float4-column, depth-2 software pipeline.
// Features 0..3583 -> q, 3584..4095 -> k, 4096..4607 -> v.
__global__ __launch_bounds__(256) void qkv_kernel(
    const float* __restrict__ hid,
    const float* __restrict__ qw, const float* __restrict__ qb,
    const float* __restrict__ kw, const float* __restrict__ kb,
    const float* __restrict__ vw, const float* __restrict__ vb,
    float* __restrict__ qout, float* __restrict__ kout, float* __restrict__ vout)
{
    const int tid = threadIdx.x;
    const int w = tid >> 6, lane = tid & 63;
    const int f = blockIdx.x * 4 + w;

    const float* W; const float* Bv; float* Out; int fb; int ostr;
    if (f < 3584)      { W = qw; Bv = qb; Out = qout; fb = f;        ostr = 3584; }
    else if (f < 4096) { W = kw; Bv = kb; Out = kout; fb = f - 3584; ostr = 512;  }
    else               { W = vw; Bv = vb; Out = vout; fb = f - 4096; ostr = 512;  }

    const float4* wr = (const float4*)(W + (size_t)fb * H);
    const float4* h4 = (const float4*)hid;

    float acc[8];
    #pragma unroll
    for (int b = 0; b < 8; ++b) acc[b] = 0.f;

    float4 wv[2], hb[2][8];
    // prime
    {
        const int c = lane;
        wv[0] = wr[c];
        #pragma unroll
        for (int b = 0; b < 8; ++b) hb[0][b] = h4[b * 896 + c];
    }
    #pragma unroll
    for (int j = 0; j < 14; ++j) {
        const int s = j & 1, ns = s ^ 1;
        if (j < 13) {
            const int c = lane + 64 * (j + 1);
            wv[ns] = wr[c];
            #pragma unroll
            for (int b = 0; b < 8; ++b) hb[ns][b] = h4[b * 896 + c];
        }
        #pragma unroll
        for (int b = 0; b < 8; ++b) acc[b] += dot4(wv[s], hb[s][b]);
    }
    #pragma unroll
    for (int b = 0; b < 8; ++b) acc[b] = red64_sum(acc[b]);

    if (lane == 0) {
        const float bias = Bv[fb];
        #pragma unroll
        for (int b = 0; b < 8; ++b) Out[b * ostr + fb] = acc[b] + bias;
    }
}

// ---------------- Kernel 2: RoPE (q in-place, k) + KV-cache scatter ----------------
// grid = 32 blocks of 256. Block = (batch b, kv-head qtr): 7 q-heads + 1 kv-head.
__global__ __launch_bounds__(256) void rope_cache_kernel(
    float* __restrict__ q, const float* __restrict__ kraw, const float* __restrict__ vraw,
    const float* __restrict__ cosb, const float* __restrict__ sinb,
    const int* __restrict__ btab, const int* __restrict__ cs,
    float* __restrict__ kpool, float* __restrict__ vpool)
{
    const int b = blockIdx.x >> 2;
    const int qtr = blockIdx.x & 3;
    const int tid = threadIdx.x;

    for (int i = tid; i < 448; i += 256) {
        const int h = qtr * 7 + (i >> 6), dp = i & 63;
        float* base = q + (size_t)b * H + h * HD;
        const float x1 = base[dp], x2 = base[dp + 64];
        const float c1 = cosb[b * HD + dp],      s1 = sinb[b * HD + dp];
        const float c2 = cosb[b * HD + dp + 64], s2 = sinb[b * HD + dp + 64];
        base[dp]      = x1 * c1 - x2 * s1;
        base[dp + 64] = x2 * c2 + x1 * s2;
    }
    const int r = b * KVH + qtr;
    const int pos = cs[r] - 1;
    const int pb = btab[r * MB + (pos >> 8)];
    const int off = pos & 255;
    if (tid < 64) {
        const int dp = tid;
        const float* kb_ = kraw + (size_t)r * HD;
        const float x1 = kb_[dp], x2 = kb_[dp + 64];
        const float c1 = cosb[b * HD + dp],      s1 = sinb[b * HD + dp];
        const float c2 = cosb[b * HD + dp + 64], s2 = sinb[b * HD + dp + 64];
        float* dst = kpool + ((size_t)pb * BS + off) * HD;
        dst[dp]      = x1 * c1 - x2 * s1;
        dst[dp + 64] = x2 * c2 + x1 * s2;
    }
    if (tid < 128) {
        vpool[((size_t)pb * BS + off) * HD + tid] = vraw[(size_t)r * HD + tid];
    }
}

// ---------------- Kernel 3: flash-decode partials (barrier-free, pipelined) ----------------
// grid = (MB pages, R rows), 256 threads = 4 independent waves, each owning a
// 64-token chunk. Explicit register-batched K/V loads for deep MLP.
__global__ __launch_bounds__(256) void attn_partial_kernel(
    const float* __restrict__ q, const float* __restrict__ kpool, const float* __restrict__ vpool,
    const int* __restrict__ btab, const int* __restrict__ cs,
    float* __restrict__ pm, float* __restrict__ pl, float* __restrict__ po)
{
    const int page = blockIdx.x;
    const int r = blockIdx.y;
    const int seqlen = cs[r];
    if ((page << 8) >= seqlen) return;

    const int tid = threadIdx.x;
    const int w = tid >> 6;            // wave -> 64-token chunk within page
    const int lane = tid & 63;
    const int chunk = page * 4 + w;
    const int c0 = chunk * 64;
    if (c0 >= seqlen) return;          // wave-uniform exit; no barriers anywhere
    const int vt = min(64, seqlen - c0);

    const int blk = btab[r * MB + page];
    const float* Kp = kpool + ((size_t)blk * BS + w * 64) * HD;
    const float* Vp = vpool + ((size_t)blk * BS + w * 64) * HD;

    __shared__ float s_p[4][GS][64];   // 7 KB: per-wave score/p buffer

    const int tl = lane >> 4;          // token within group of 4
    const int dg = lane & 15;          // dim-group: dims [dg*8, dg*8+8)

    // q fragments: 7 heads x 8 dims per lane (56 VGPR)
    float4 qa[GS], qb2[GS];
    #pragma unroll
    for (int g = 0; g < GS; ++g) {
        const float4* qp = (const float4*)(q + (size_t)(r * GS + g) * HD + dg * 8);
        qa[g] = qp[0]; qb2[g] = qp[1];
    }

    // ---- Phase A: scores, 4 batches of 16 tokens, 2 in flight ----
    float4 ka[2][4][2];
    #define LOADK(slot, base)                                                        \
        { _Pragma("unroll")                                                          \
          for (int i = 0; i < 4; ++i) {                                              \
              const float4* p_ = (const float4*)(Kp + (size_t)((base) + i*4 + tl)*HD + dg*8); \
              ka[slot][i][0] = p_[0]; ka[slot][i][1] = p_[1];                        \
          } }
    #define COMPK(slot, base)                                                        \
        { _Pragma("unroll")                                                          \
          for (int i = 0; i < 4; ++i) {                                              \
              const int t_ = (base) + i*4 + tl;                                      \
              _Pragma("unroll")                                                      \
              for (int g = 0; g < GS; ++g) {                                         \
                  float v_ = dot4(qa[g], ka[slot][i][0]) + dot4(qb2[g], ka[slot][i][1]); \
                  v_ = red16(v_);                                                    \
                  if (dg == 0) s_p[w][g][t_] = v_ * SCALE;                           \
              } } }
    LOADK(0, 0)  LOADK(1, 16)
    COMPK(0, 0)  LOADK(0, 32)
    COMPK(1, 16) LOADK(1, 48)
    COMPK(0, 32) COMPK(1, 48)
    #undef LOADK
    #undef COMPK

    // ---- prefetch first two V batches (overlaps softmax) ----
    float2 vv[2][8];
    #define LOADV(slot, base)                                                        \
        { _Pragma("unroll")                                                          \
          for (int k = 0; k < 8; ++k)                                                \
              vv[slot][k] = *(const float2*)(Vp + (size_t)((base) + k)*HD + lane*2); }
    LOADV(0, 0) LOADV(1, 8)

    // ---- Phase B: per-chunk softmax partial. Lane = token. ----
    float mx[GS], lsum[GS];
    #pragma unroll
    for (int g = 0; g < GS; ++g) {
        const float sv = (lane < vt) ? s_p[w][g][lane] : -3.0e38f;
        const float m_ = red64_max(sv);
        const float p = (lane < vt) ? __expf(sv - m_) : 0.f;
        s_p[w][g][lane] = p;                 // zeros out tail garbage too
        lsum[g] = red64_sum(p);
        mx[g] = m_;
    }
    const size_t pidx = (size_t)(r * NCHUNK + chunk) * GS;
    if (lane == 0) {
        #pragma unroll
        for (int g = 0; g < GS; ++g) { pm[pidx + g] = mx[g]; pl[pidx + g] = lsum[g]; }
    }

    // ---- Phase C: PV, 8 batches of 8 tokens, 2 in flight. Lane = 2 dims. ----
    float acc[GS][2];
    #pragma unroll
    for (int g = 0; g < GS; ++g) { acc[g][0] = 0.f; acc[g][1] = 0.f; }
    #define COMPV(slot, base)                                                        \
        { _Pragma("unroll")                                                          \
          for (int g = 0; g < GS; ++g) {                                             \
              const float4 p0 = *(const float4*)&s_p[w][g][base];                    \
              const float4 p1 = *(const float4*)&s_p[w][g][(base) + 4];              \
              acc[g][0] = fmaf(p0.x, vv[slot][0].x, acc[g][0]);                      \
              acc[g][1] = fmaf(p0.x, vv[slot][0].y, acc[g][1]);                      \
              acc[g][0] = fmaf(p0.y, vv[slot][1].x, acc[g][0]);                      \
              acc[g][1] = fmaf(p0.y, vv[slot][1].y, acc[g][1]);                      \
              acc[g][0] = fmaf(p0.z, vv[slot][2].x, acc[g][0]);                      \
              acc[g][1] = fmaf(p0.z, vv[slot][2].y, acc[g][1]);                      \
              acc[g][0] = fmaf(p0.w, vv[slot][3].x, acc[g][0]);                      \
              acc[g][1] = fmaf(p0.w, vv[slot][3].y, acc[g][1]);                      \
              acc[g][0] = fmaf(p1.x, vv[slot][4].x, acc[g][0]);                      \
              acc[g][1] = fmaf(p1.x, vv[slot][4].y, acc[g][1]);                      \
              acc[g][0] = fmaf(p1.y, vv[slot][5].x, acc[g][0]);                      \
              acc[g][1] = fmaf(p1.y, vv[slot][5].y, acc[g][1]);                      \
              acc[g][0] = fmaf(p1.z, vv[slot][6].x, acc[g][0]);                      \
              acc[g][1] = fmaf(p1.z, vv[slot][6].y, acc[g][1]);                      \
              acc[g][0] = fmaf(p1.w, vv[slot][7].x, acc[g][0]);                      \
              acc[g][1] = fmaf(p1.w, vv[slot][7].y, acc[g][1]);                      \
          } }
    COMPV(0, 0)  LOADV(0, 16)
    COMPV(1, 8)  LOADV(1, 24)
    COMPV(0, 16) LOADV(0, 32)
    COMPV(1, 24) LOADV(1, 40)
    COMPV(0, 32) LOADV(0, 48)
    COMPV(1, 40) LOADV(1, 56)
    COMPV(0, 48) COMPV(1, 56)
    #undef LOADV
    #undef COMPV

    #pragma unroll
    for (int g = 0; g < GS; ++g) {
        *(float2*)(po + (pidx + g) * HD + lane * 2) = make_float2(acc[g][0], acc[g][1]);
    }
}

// ---------------- Kernel 4: combine chunk partials (online softmax) ----------------
// grid = R*GS blocks of 128 (thread = dim).
__global__ __launch_bounds__(128) void combine_kernel(
    const float* __restrict__ pm, const float* __restrict__ pl, const float* __restrict__ po,
    const int* __restrict__ cs, float* __restrict__ att)
{
    const int bx = blockIdx.x;
    const int r = bx / GS, g = bx % GS;
    const int nc = (cs[r] + 63) >> 6;
    const int d = threadIdx.x;
    float M = -3.0e38f, L = 0.f, acc = 0.f;
    for (int c = 0; c < nc; ++c) {
        const size_t idx = (size_t)(r * NCHUNK + c) * GS + g;
        const float m = pm[idx];
        const float nM = fmaxf(M, m);
        const float sc = __expf(M - nM);
        const float wg = __expf(m - nM);
        acc = acc * sc + wg * po[idx * HD + d];
        L   = L   * sc + wg * pl[idx];
        M = nM;
    }
    att[(size_t)(r * GS + g) * HD + d] = acc / L;
}

// ---------------- Kernel 5: O projection GEMV ----------------
// grid = 896 blocks x 256; same structure as qkv (no bias), out stride H.
__global__ __launch_bounds__(256) void oproj_kernel(
    const float* __restrict__ att, const float* __restrict__ ow, float* __restrict__ out)
{
    const int tid = threadIdx.x;
    const int w = tid >> 6, lane = tid & 63;
    const int f = blockIdx.x * 4 + w;

    const float4* wr = (const float4*)(ow + (size_t)f * H);
    const float4* a4 = (const float4*)att;

    float acc[8];
    #pragma unroll
    for (int b = 0; b < 8; ++b) acc[b] = 0.f;

    float4 wv[2], hb[2][8];
    {
        const int c = lane;
        wv[0] = wr[c];
        #pragma unroll
        for (int b = 0; b < 8; ++b) hb[0][b] = a4[b * 896 + c];
    }
    #pragma unroll
    for (int j = 0; j < 14; ++j) {
        const int s = j & 1, ns = s ^ 1;
        if (j < 13) {
            const int c = lane + 64 * (j + 1);
            wv[ns] = wr[c];
            #pragma unroll
            for (int b = 0; b < 8; ++b) hb[ns][b] = a4[b * 896 + c];
        }
        #pragma unroll
        for (int b = 0; b < 8; ++b) acc[b] += dot4(wv[s], hb[s][b]);
    }
    #pragma unroll
    for (int b = 0; b < 8; ++b) acc[b] = red64_sum(acc[b]);

    if (lane == 0) {
        #pragma unroll
        for (int b = 0; b < 8; ++b) out[b * H + f] = acc[b];
    }
}

extern "C" void kernel_launch(void* const* d_in, const int* in_sizes, int n_in,
                              void* d_out, int out_size, void* d_ws, size_t ws_size,
                              hipStream_t stream) {
    (void)in_sizes; (void)n_in; (void)out_size; (void)ws_size;
    const float* hid  = (const float*)d_in[0];
    const float* cosb = (const float*)d_in[1];
    const float* sinb = (const float*)d_in[2];
    const float* qw   = (const float*)d_in[3];
    const float* qb   = (const float*)d_in[4];
    const float* kw   = (const float*)d_in[5];
    const float* kb   = (const float*)d_in[6];
    const float* vw   = (const float*)d_in[7];
    const float* vb   = (const float*)d_in[8];
    const float* ow   = (const float*)d_in[9];
    float* kpool      = (float*)d_in[10];
    float* vpool      = (float*)d_in[11];
    const int* btab   = (const int*)d_in[12];
    const int* cs     = (const int*)d_in[13];

    float* ws   = (float*)d_ws;
    float* q    = ws;             // 28672
    float* kraw = q + 28672;      // 4096
    float* vraw = kraw + 4096;    // 4096
    float* att  = vraw + 4096;    // 28672
    float* pm   = att + 28672;    // R*NCHUNK*GS = 14336
    float* pl   = pm + 14336;     // 14336
    float* po   = pl + 14336;     // R*NCHUNK*GS*HD = 1835008 (~7.3 MB)

    hipLaunchKernelGGL(qkv_kernel, dim3(1152), dim3(256), 0, stream,
                       hid, qw, qb, kw, kb, vw, vb, q, kraw, vraw);
    hipLaunchKernelGGL(rope_cache_kernel, dim3(32), dim3(256), 0, stream,
                       q, kraw, vraw, cosb, sinb, btab, cs, kpool, vpool);
    hipLaunchKernelGGL(attn_partial_kernel, dim3(MB, R), dim3(256), 0, stream,
                       q, kpool, vpool, btab, cs, pm, pl, po);
    hipLaunchKernelGGL(combine_kernel, dim3(R * GS), dim3(128), 0, stream,
                       pm, pl, po, cs, att);
    hipLaunchKernelGGL(oproj_kernel, dim3(896), dim3(256), 0, stream,
                       att, ow, (float*)d_out);
}